// Round 7
// baseline (108580.908 us; speedup 1.0000x reference)
//
#include <hip/hip_runtime.h>
#include <cstdint>
#include <cstddef>

#define TDIM 512
#define BDIM 64
#define IDIM 512
#define HDIM 1024
#define BH (BDIM * HDIM)

__device__ __forceinline__ float sigmf(float x) { return 1.0f / (1.0f + __expf(-x)); }
__device__ __forceinline__ float dot4(float4 a, float4 b) {
  return a.x * b.x + a.y * b.y + a.z * b.z + a.w * b.w;
}

// ---------------- GRU one timestep, both directions (launch-per-step) ----------------
// grid = 256 blocks: dir = blk>>7, cgrp = blk&127 (8 cols each). 256 threads:
// cl = tid&7 (col within group), bq = tid>>3 (0..31) -> batches b0=2bq, b1=2bq+1.
__global__ __launch_bounds__(256) void k_gru_step(
    const float* __restrict__ x,
    const float* __restrict__ wih_f, const float* __restrict__ whh_f,
    const float* __restrict__ bih_f, const float* __restrict__ bhh_f,
    const float* __restrict__ wih_b, const float* __restrict__ whh_b,
    const float* __restrict__ bih_b, const float* __restrict__ bhh_b,
    const float* __restrict__ attw,
    float* __restrict__ hgru, float* __restrict__ attp, int t) {
  const int blk = blockIdx.x;
  const int dir = blk >> 7, cgrp = blk & 127;
  const int tid = threadIdx.x;
  const int cl = tid & 7, bq = tid >> 3;
  const int col = cgrp * 8 + cl;
  const int b0 = bq * 2, b1 = b0 + 1;
  const int tt = dir ? (TDIM - 1 - t) : t;
  const float* wih = dir ? wih_b : wih_f;
  const float* whh = dir ? whh_b : whh_f;
  const float* bih = dir ? bih_b : bih_f;
  const float* bhh = dir ? bhh_b : bhh_f;
  float* hb = hgru + (size_t)dir * 2 * BH;
  const float* h_in = hb + (size_t)(t & 1) * BH;
  float* h_out = hb + (size_t)((t + 1) & 1) * BH;

  float aR0 = 0.f, aR1 = 0.f, aZ0 = 0.f, aZ1 = 0.f;
  float aN0 = 0.f, aN1 = 0.f, aH0 = 0.f, aH1 = 0.f;

  // x-projection part: K = 512
  {
    const float4* wr = (const float4*)(wih + (size_t)col * IDIM);
    const float4* wz = (const float4*)(wih + (size_t)(HDIM + col) * IDIM);
    const float4* wn = (const float4*)(wih + (size_t)(2 * HDIM + col) * IDIM);
    const float4* x0 = (const float4*)(x + ((size_t)b0 * TDIM + tt) * IDIM);
    const float4* x1 = (const float4*)(x + ((size_t)b1 * TDIM + tt) * IDIM);
#pragma unroll 4
    for (int k = 0; k < IDIM / 4; ++k) {
      float4 w0 = wr[k], w1 = wz[k], w2 = wn[k];
      float4 u = x0[k], v = x1[k];
      aR0 += dot4(w0, u); aR1 += dot4(w0, v);
      aZ0 += dot4(w1, u); aZ1 += dot4(w1, v);
      aN0 += dot4(w2, u); aN1 += dot4(w2, v);
    }
  }
  // h-projection part: K = 1024
  {
    const float4* wr = (const float4*)(whh + (size_t)col * HDIM);
    const float4* wz = (const float4*)(whh + (size_t)(HDIM + col) * HDIM);
    const float4* wn = (const float4*)(whh + (size_t)(2 * HDIM + col) * HDIM);
    const float4* h0 = (const float4*)(h_in + (size_t)b0 * HDIM);
    const float4* h1 = (const float4*)(h_in + (size_t)b1 * HDIM);
#pragma unroll 4
    for (int k = 0; k < HDIM / 4; ++k) {
      float4 w0 = wr[k], w1 = wz[k], w2 = wn[k];
      float4 u = h0[k], v = h1[k];
      aR0 += dot4(w0, u); aR1 += dot4(w0, v);
      aZ0 += dot4(w1, u); aZ1 += dot4(w1, v);
      aH0 += dot4(w2, u); aH1 += dot4(w2, v);
    }
  }

  const float br = bih[col] + bhh[col];
  const float bz = bih[col + HDIM] + bhh[col + HDIM];
  const float bnx = bih[col + 2 * HDIM];
  const float bnh = bhh[col + 2 * HDIM];
  const float wfc = attw[dir * HDIM + col];

  float hold0 = h_in[(size_t)b0 * HDIM + col];
  float hold1 = h_in[(size_t)b1 * HDIM + col];
  float r0 = sigmf(aR0 + br), r1 = sigmf(aR1 + br);
  float z0 = sigmf(aZ0 + bz), z1 = sigmf(aZ1 + bz);
  float n0 = tanhf(aN0 + bnx + r0 * (aH0 + bnh));
  float n1 = tanhf(aN1 + bnx + r1 * (aH1 + bnh));
  float hn0 = (1.0f - z0) * n0 + z0 * hold0;
  float hn1 = (1.0f - z1) * n1 + z1 * hold1;
  h_out[(size_t)b0 * HDIM + col] = hn0;
  h_out[(size_t)b1 * HDIM + col] = hn1;

  // attention partial: sum over this block's 8 cols of h*w_fc
  float s0 = hn0 * wfc, s1 = hn1 * wfc;
  s0 += __shfl_xor(s0, 1, 64); s1 += __shfl_xor(s1, 1, 64);
  s0 += __shfl_xor(s0, 2, 64); s1 += __shfl_xor(s1, 2, 64);
  s0 += __shfl_xor(s0, 4, 64); s1 += __shfl_xor(s1, 4, 64);
  if (cl == 0) {
    float* ap = attp + (size_t)blk * (TDIM * BDIM) + (size_t)tt * BDIM;
    ap[b0] = s0;
    ap[b1] = s1;
  }
}

// ---------------- attention finalize (f32 outputs) ----------------
__global__ __launch_bounds__(256) void k_attf(const float* __restrict__ attp,
                                              const float* __restrict__ fcb,
                                              float* __restrict__ att,
                                              float* __restrict__ att_out) {
  int idx = blockIdx.x * 256 + threadIdx.x;  // T*B
  float s = fcb[0];
  for (int g = 0; g < 256; ++g) s += attp[(size_t)g * (TDIM * BDIM) + idx];
  float a = sigmf(3.0f * s);
  att[idx] = a;
  int t = idx >> 6, b = idx & 63;
  att_out[(size_t)b * TDIM + t] = a;  // att^T, float32
}

// ---------------- attention-gated scan, one timestep ----------------
__global__ __launch_bounds__(256) void k_scan3_step(
    const float* __restrict__ x,
    const float* __restrict__ i2h_w, const float* __restrict__ h2h_w,
    const float* __restrict__ i2hb, const float* __restrict__ h2hb,
    const float* __restrict__ att,
    float* __restrict__ h3, int t) {
  const int cgrp = blockIdx.x;
  const int tid = threadIdx.x;
  const int cl = tid & 7, bq = tid >> 3;
  const int col = cgrp * 8 + cl;
  const int b0 = bq * 2, b1 = b0 + 1;
  const float* h_in = h3 + (size_t)(t & 1) * BH;
  float* h_out = h3 + (size_t)((t + 1) & 1) * BH;

  float a0 = 0.f, a1 = 0.f;
  {
    const float4* w = (const float4*)(i2h_w + (size_t)col * IDIM);
    const float4* x0 = (const float4*)(x + ((size_t)b0 * TDIM + t) * IDIM);
    const float4* x1 = (const float4*)(x + ((size_t)b1 * TDIM + t) * IDIM);
#pragma unroll 4
    for (int k = 0; k < IDIM / 4; ++k) {
      float4 wv = w[k];
      a0 += dot4(wv, x0[k]);
      a1 += dot4(wv, x1[k]);
    }
  }
  {
    const float4* w = (const float4*)(h2h_w + (size_t)col * HDIM);
    const float4* h0 = (const float4*)(h_in + (size_t)b0 * HDIM);
    const float4* h1 = (const float4*)(h_in + (size_t)b1 * HDIM);
#pragma unroll 4
    for (int k = 0; k < HDIM / 4; ++k) {
      float4 wv = w[k];
      a0 += dot4(wv, h0[k]);
      a1 += dot4(wv, h1[k]);
    }
  }
  const float bc = i2hb[col] + h2hb[col];
  float hold0 = h_in[(size_t)b0 * HDIM + col];
  float hold1 = h_in[(size_t)b1 * HDIM + col];
  float g0 = att[(size_t)t * BDIM + b0];
  float g1 = att[(size_t)t * BDIM + b1];
  float tr0 = fmaxf(a0 + bc, 0.0f);
  float tr1 = fmaxf(a1 + bc, 0.0f);
  h_out[(size_t)b0 * HDIM + col] = g0 * tr0 + (1.0f - g0) * hold0;
  h_out[(size_t)b1 * HDIM + col] = g1 * tr1 + (1.0f - g1) * hold1;
}

// ---------------- final FC (fp32 in, fp32 out) ----------------
__global__ __launch_bounds__(256) void k_fc(const float* __restrict__ A,
                                            const float* __restrict__ W,
                                            const float* __restrict__ bias,
                                            float* __restrict__ dst) {
  const int idx = blockIdx.x * 256 + threadIdx.x;
  const int rr = idx >> 10, c = idx & 1023;
  const float4* a = (const float4*)(A + (size_t)rr * HDIM);
  const float4* w = (const float4*)(W + (size_t)c * HDIM);
  float s = bias[c];
  for (int k = 0; k < HDIM / 4; ++k) s += dot4(a[k], w[k]);
  dst[idx] = s;
}

// ---------------- diagnostic (f32) ----------------
__global__ __launch_bounds__(256) void k_diag(float* out, int n, float val) {
  int i = blockIdx.x * 256 + threadIdx.x;
  if (i < n) out[i] = val;
}

extern "C" void kernel_launch(void* const* d_in, const int* in_sizes, int n_in,
                              void* d_out, int out_size, void* d_ws, size_t ws_size,
                              hipStream_t stream) {
  float* outF = (float*)d_out;
  int diag_blocks = (out_size + 255) / 256;

  // input-shape tripwire (validated in round 6: does not fire)
  static const int exp_sizes[19] = {16777216, 1572864, 3145728, 3072, 3072,
                                    1572864, 3145728, 3072, 3072, 2048, 1,
                                    524288, 1024, 1048576, 1024, 1048576, 1024,
                                    1048576, 1024};
  if (n_in != 19) {
    k_diag<<<diag_blocks, 256, 0, stream>>>(outF, out_size, 3999.0f);
    return;
  }
  for (int i = 0; i < 19; ++i) {
    if (in_sizes[i] != exp_sizes[i]) {
      k_diag<<<diag_blocks, 256, 0, stream>>>(outF, out_size, (float)(4000 + i * 16));
      return;
    }
  }

  const float* x     = (const float*)d_in[0];
  const float* wih_f = (const float*)d_in[1];
  const float* whh_f = (const float*)d_in[2];
  const float* bih_f = (const float*)d_in[3];
  const float* bhh_f = (const float*)d_in[4];
  const float* wih_b = (const float*)d_in[5];
  const float* whh_b = (const float*)d_in[6];
  const float* bih_b = (const float*)d_in[7];
  const float* bhh_b = (const float*)d_in[8];
  const float* fc_w  = (const float*)d_in[9];
  const float* fc_b  = (const float*)d_in[10];
  const float* i2h_w = (const float*)d_in[11];
  const float* i2h_b = (const float*)d_in[12];
  const float* h2h_w = (const float*)d_in[13];
  const float* h2h_b = (const float*)d_in[14];
  const float* fc0_w = (const float*)d_in[15];
  const float* fc0_b = (const float*)d_in[16];
  const float* fc1_w = (const float*)d_in[17];
  const float* fc1_b = (const float*)d_in[18];

  const size_t OFF_ATTP = 0;          // 256 * T*B * 4 = 33,554,432
  const size_t OFF_ATT  = 33554432;   // 131,072
  const size_t OFF_HGRU = 33685504;   // 2,097,152
  const size_t OFF_H3   = 35782656;   // 524,288
  const size_t OFF_OUT1 = 36306944;   // 262,144
  const size_t TOTAL    = 36569088;

  if (ws_size < TOTAL) {
    k_diag<<<diag_blocks, 256, 0, stream>>>(outF, out_size, (float)(ws_size >> 20));
    return;
  }

  char* ws = (char*)d_ws;
  float* attp = (float*)(ws + OFF_ATTP);
  float* att  = (float*)(ws + OFF_ATT);
  float* hgru = (float*)(ws + OFF_HGRU);
  float* h3   = (float*)(ws + OFF_H3);
  float* out1 = (float*)(ws + OFF_OUT1);

  hipMemsetAsync(hgru, 0, 2 * 2 * BH * 4, stream);
  hipMemsetAsync(h3, 0, 2 * BH * 4, stream);

  for (int t = 0; t < TDIM; ++t)
    k_gru_step<<<256, 256, 0, stream>>>(x, wih_f, whh_f, bih_f, bhh_f,
                                        wih_b, whh_b, bih_b, bhh_b, fc_w,
                                        hgru, attp, t);

  k_attf<<<128, 256, 0, stream>>>(attp, fc_b, att, outF + 65536);

  for (int t = 0; t < TDIM; ++t)
    k_scan3_step<<<128, 256, 0, stream>>>(x, i2h_w, h2h_w, i2h_b, h2h_b, att, h3, t);

  // final h3 state lives in buffer 0 (TDIM even)
  k_fc<<<256, 256, 0, stream>>>(h3, fc0_w, fc0_b, out1);
  k_fc<<<256, 256, 0, stream>>>(out1, fc1_w, fc1_b, outF);
}

// Round 9
// 30013.309 us; speedup vs baseline: 3.6178x; 3.6178x over previous
//
#include <hip/hip_runtime.h>
#include <cstdint>
#include <cstddef>

#define TDIM 512
#define BDIM 64
#define IDIM 512
#define HDIM 1024
#define SPIN_CAP 100000u  // hang-safety: converts any deadlock into a wrong answer

typedef __attribute__((ext_vector_type(8))) short s16x8;
typedef __attribute__((ext_vector_type(4))) float f32x4;

__device__ __forceinline__ unsigned short f2bf(float f) {
  unsigned u = __builtin_bit_cast(unsigned, f);
  u += 0x7FFFu + ((u >> 16) & 1u);
  return (unsigned short)(u >> 16);
}
__device__ __forceinline__ float bf2f(unsigned short s) {
  unsigned u = ((unsigned)s) << 16;
  return __builtin_bit_cast(float, u);
}
__device__ __forceinline__ float sigmf(float x) { return 1.0f / (1.0f + __expf(-x)); }
__device__ __forceinline__ unsigned pk2(float a, float b) {
  return (unsigned)f2bf(a) | ((unsigned)f2bf(b) << 16);
}
#define MFMA16(a, b, c) __builtin_amdgcn_mfma_f32_16x16x32_bf16((a), (b), (c), 0, 0, 0)

// ---------------- converts ----------------
__global__ __launch_bounds__(256) void k_xcvt(const float* __restrict__ x,
                                              unsigned short* __restrict__ xbf) {
  int idx = blockIdx.x * 256 + threadIdx.x;  // T*B*I/8 threads
  int i8 = idx * 8;
  int i = i8 & (IDIM - 1);
  int tb = i8 >> 9;
  int t = tb >> 6, b = tb & 63;
  const float* src = x + ((size_t)(b * TDIM + t)) * IDIM + i;
  float4 a = *(const float4*)src;
  float4 c = *(const float4*)(src + 4);
  uint4 v;
  v.x = pk2(a.x, a.y); v.y = pk2(a.z, a.w);
  v.z = pk2(c.x, c.y); v.w = pk2(c.z, c.w);
  *(uint4*)(xbf + i8) = v;
}

__global__ __launch_bounds__(256) void k_cvt(const float* __restrict__ src,
                                             unsigned short* __restrict__ dst) {
  size_t i8 = ((size_t)blockIdx.x * 256 + threadIdx.x) * 8;
  float4 a = *(const float4*)(src + i8);
  float4 c = *(const float4*)(src + i8 + 4);
  uint4 v;
  v.x = pk2(a.x, a.y); v.y = pk2(a.z, a.w);
  v.z = pk2(c.x, c.y); v.w = pk2(c.z, c.w);
  *(uint4*)(dst + i8) = v;
}

// ---------------- fused persistent bidirectional GRU ----------------
// grid = 128 WGs x 256 thr (4 waves). dir = wg>>6, cg = wg&63 owns 16 h-cols.
// Wave wv owns batch m-tile [wv*16, wv*16+16). Weights (whh 96KB + wih 48KB) in LDS.
__global__ __launch_bounds__(256, 1) void k_gru_fused(
    const unsigned short* __restrict__ xbf,
    const unsigned short* __restrict__ wih_f, const unsigned short* __restrict__ wih_b,
    const unsigned short* __restrict__ whh_f, const unsigned short* __restrict__ whh_b,
    const float* __restrict__ bih_f, const float* __restrict__ bhh_f,
    const float* __restrict__ bih_b, const float* __restrict__ bhh_b,
    const float* __restrict__ attw,
    unsigned short* __restrict__ hbuf, float* __restrict__ attp,
    unsigned int* __restrict__ flags) {
  __shared__ uint4 lds4[147456 / 16];  // 96KB whh + 48KB wih
  char* lds = (char*)lds4;
  const int wg = blockIdx.x, dir = wg >> 6, cg = wg & 63;
  const int tid = threadIdx.x, wv = tid >> 6, l = tid & 63;
  const int r = l & 15, q = l >> 4;
  const int col = cg * 16 + r;
  const unsigned short* wih = dir ? wih_b : wih_f;
  const unsigned short* whh = dir ? whh_b : whh_f;
  const float* bih = dir ? bih_b : bih_f;
  const float* bhh = dir ? bhh_b : bhh_f;
  unsigned int* myflags = flags + dir * 64;
  unsigned short* hb0 = hbuf + (size_t)dir * (2 * BDIM * HDIM);

  // stage whh: 48 rows (3 gates x 16 cols) x 1024, XOR-swizzled
  for (int it = tid; it < 48 * 128; it += 256) {
    int row = it >> 7, ch = it & 127;
    int g = row >> 4, rr = row & 15;
    uint4 v = *(const uint4*)(whh + ((size_t)(g * HDIM + cg * 16 + rr)) * HDIM + ch * 8);
    *(uint4*)(lds + row * 2048 + ((ch * 16) ^ ((row & 7) << 4))) = v;
  }
  // stage wih: 48 rows x 512
  for (int it = tid; it < 48 * 64; it += 256) {
    int row = it >> 6, ch = it & 63;
    int g = row >> 4, rr = row & 15;
    uint4 v = *(const uint4*)(wih + ((size_t)(g * HDIM + cg * 16 + rr)) * IDIM + ch * 8);
    *(uint4*)(lds + 98304 + row * 1024 + ((ch * 16) ^ ((row & 7) << 4))) = v;
  }
  __syncthreads();

  const float br = bih[col] + bhh[col];
  const float bz = bih[col + HDIM] + bhh[col + HDIM];
  const float bnx = bih[col + 2 * HDIM];
  const float bnh = bhh[col + 2 * HDIM];
  const float wfc = attw[dir * HDIM + col];
  const int swz = (r & 7) << 4;
  float h[4] = {0.f, 0.f, 0.f, 0.f};

  for (int t = 0; t < TDIM; ++t) {
    if (t > 0) {
      for (unsigned spin = 0;; ++spin) {
        unsigned v = __hip_atomic_load(&myflags[l], __ATOMIC_ACQUIRE, __HIP_MEMORY_SCOPE_AGENT);
        if (__all((int)(v >= (unsigned)t))) break;
        if (spin > SPIN_CAP) break;  // watchdog
        __builtin_amdgcn_s_sleep(1);
      }
      __threadfence();
    }
    const int tt = dir ? (TDIM - 1 - t) : t;
    f32x4 aR = {}, aZ = {}, aNx = {}, aNh = {};
    {
      const unsigned short* px = xbf + ((size_t)(tt * BDIM + wv * 16 + r)) * IDIM + q * 8;
#pragma unroll 4
      for (int kt = 0; kt < 16; ++kt) {
        s16x8 a = *(const s16x8*)(px + kt * 32);
        int kb = q * 16 + kt * 64;
        s16x8 b0 = *(const s16x8*)(lds + 98304 + r * 1024 + (kb ^ swz));
        s16x8 b1 = *(const s16x8*)(lds + 98304 + (16 + r) * 1024 + (kb ^ swz));
        s16x8 b2 = *(const s16x8*)(lds + 98304 + (32 + r) * 1024 + (kb ^ swz));
        aR = MFMA16(a, b0, aR);
        aZ = MFMA16(a, b1, aZ);
        aNx = MFMA16(a, b2, aNx);
      }
    }
    {
      const unsigned short* ph = hb0 + (size_t)(t & 1) * (BDIM * HDIM) + (wv * 16 + r) * HDIM + q * 8;
#pragma unroll 4
      for (int kt = 0; kt < 32; ++kt) {
        s16x8 a = *(const s16x8*)(ph + kt * 32);
        int kb = q * 16 + kt * 64;
        s16x8 b0 = *(const s16x8*)(lds + r * 2048 + (kb ^ swz));
        s16x8 b1 = *(const s16x8*)(lds + (16 + r) * 2048 + (kb ^ swz));
        s16x8 b2 = *(const s16x8*)(lds + (32 + r) * 2048 + (kb ^ swz));
        aR = MFMA16(a, b0, aR);
        aZ = MFMA16(a, b1, aZ);
        aNh = MFMA16(a, b2, aNh);
      }
    }
    unsigned short* hn = hb0 + (size_t)((t + 1) & 1) * (BDIM * HDIM);
    float* ap = attp + (size_t)wg * (TDIM * BDIM) + tt * BDIM;
#pragma unroll
    for (int j = 0; j < 4; ++j) {
      const int b = wv * 16 + q * 4 + j;
      float rg = sigmf(aR[j] + br);
      float zg = sigmf(aZ[j] + bz);
      float ng = tanhf(aNx[j] + bnx + rg * (aNh[j] + bnh));
      float hv = (1.0f - zg) * ng + zg * h[j];
      h[j] = hv;
      hn[b * HDIM + col] = f2bf(hv);
      float s = hv * wfc;
      s += __shfl_xor(s, 1, 64);
      s += __shfl_xor(s, 2, 64);
      s += __shfl_xor(s, 4, 64);
      s += __shfl_xor(s, 8, 64);
      if (r == 0) ap[b] = s;
    }
    __threadfence();
    __syncthreads();
    if (tid == 0)
      __hip_atomic_store(&myflags[cg], (unsigned)(t + 1), __ATOMIC_RELEASE, __HIP_MEMORY_SCOPE_AGENT);
  }
}

// ---------------- attention finalize (f32 outputs) ----------------
__global__ __launch_bounds__(256) void k_attf(const float* __restrict__ attp,
                                              const float* __restrict__ fcb,
                                              float* __restrict__ att,
                                              float* __restrict__ att_out) {
  int idx = blockIdx.x * 256 + threadIdx.x;  // T*B
  float s = fcb[0];
  for (int w = 0; w < 128; ++w) s += attp[(size_t)w * (TDIM * BDIM) + idx];
  float a = sigmf(3.0f * s);
  att[idx] = a;
  int t = idx >> 6, b = idx & 63;
  att_out[(size_t)b * TDIM + t] = a;  // att^T, float32
}

// ---------------- fused persistent attention-gated scan ----------------
__global__ __launch_bounds__(256, 1) void k_scan3(
    const unsigned short* __restrict__ xbf,
    const unsigned short* __restrict__ i2h16, const unsigned short* __restrict__ h2h16,
    const float* __restrict__ i2hb, const float* __restrict__ h2hb,
    const float* __restrict__ att,
    unsigned short* __restrict__ h3buf, float* __restrict__ hlast,
    unsigned int* __restrict__ flags3) {
  __shared__ uint4 lds4[49152 / 16];  // 32KB h2h + 16KB i2h
  char* lds = (char*)lds4;
  const int cg = blockIdx.x;
  const int tid = threadIdx.x, wv = tid >> 6, l = tid & 63;
  const int r = l & 15, q = l >> 4;
  const int col = cg * 16 + r;
  for (int it = tid; it < 16 * 128; it += 256) {
    int row = it >> 7, ch = it & 127;
    uint4 v = *(const uint4*)(h2h16 + ((size_t)(cg * 16 + row)) * HDIM + ch * 8);
    *(uint4*)(lds + row * 2048 + ((ch * 16) ^ ((row & 7) << 4))) = v;
  }
  for (int it = tid; it < 16 * 64; it += 256) {
    int row = it >> 6, ch = it & 63;
    uint4 v = *(const uint4*)(i2h16 + ((size_t)(cg * 16 + row)) * IDIM + ch * 8);
    *(uint4*)(lds + 32768 + row * 1024 + ((ch * 16) ^ ((row & 7) << 4))) = v;
  }
  __syncthreads();
  const float bc = i2hb[col] + h2hb[col];
  const int swz = (r & 7) << 4;
  float h[4] = {0.f, 0.f, 0.f, 0.f};
  for (int t = 0; t < TDIM; ++t) {
    if (t > 0) {
      for (unsigned spin = 0;; ++spin) {
        unsigned v = __hip_atomic_load(&flags3[l], __ATOMIC_ACQUIRE, __HIP_MEMORY_SCOPE_AGENT);
        if (__all((int)(v >= (unsigned)t))) break;
        if (spin > SPIN_CAP) break;  // watchdog
        __builtin_amdgcn_s_sleep(1);
      }
      __threadfence();
    }
    f32x4 ac = {};
    {
      const unsigned short* px = xbf + ((size_t)(t * BDIM + wv * 16 + r)) * IDIM + q * 8;
#pragma unroll 4
      for (int kt = 0; kt < 16; ++kt) {
        s16x8 a = *(const s16x8*)(px + kt * 32);
        int kb = q * 16 + kt * 64;
        s16x8 b = *(const s16x8*)(lds + 32768 + r * 1024 + (kb ^ swz));
        ac = MFMA16(a, b, ac);
      }
    }
    {
      const unsigned short* ph = h3buf + (size_t)(t & 1) * (BDIM * HDIM) + (wv * 16 + r) * HDIM + q * 8;
#pragma unroll 4
      for (int kt = 0; kt < 32; ++kt) {
        s16x8 a = *(const s16x8*)(ph + kt * 32);
        int kb = q * 16 + kt * 64;
        s16x8 b = *(const s16x8*)(lds + r * 2048 + (kb ^ swz));
        ac = MFMA16(a, b, ac);
      }
    }
    unsigned short* hn = h3buf + (size_t)((t + 1) & 1) * (BDIM * HDIM);
    const float* ab = att + (size_t)t * BDIM;
#pragma unroll
    for (int j = 0; j < 4; ++j) {
      const int b = wv * 16 + q * 4 + j;
      float tr = fmaxf(ac[j] + bc, 0.0f);
      float a = ab[b];
      float hv = a * tr + (1.0f - a) * h[j];
      h[j] = hv;
      hn[b * HDIM + col] = f2bf(hv);
    }
    __threadfence();
    __syncthreads();
    if (tid == 0)
      __hip_atomic_store(&flags3[cg], (unsigned)(t + 1), __ATOMIC_RELEASE, __HIP_MEMORY_SCOPE_AGENT);
  }
#pragma unroll
  for (int j = 0; j < 4; ++j) {
    const int b = wv * 16 + q * 4 + j;
    hlast[b * HDIM + col] = h[j];
  }
}

// ---------------- final FC (fp32 in, fp32 out) ----------------
__global__ __launch_bounds__(256) void k_fc(const float* __restrict__ A,
                                            const float* __restrict__ W,
                                            const float* __restrict__ bias,
                                            float* __restrict__ dst) {
  const int idx = blockIdx.x * 256 + threadIdx.x;
  const int rr = idx >> 10, c = idx & 1023;
  const float4* a = (const float4*)(A + (size_t)rr * HDIM);
  const float4* w = (const float4*)(W + (size_t)c * HDIM);
  float s = bias[c];
  for (int k = 0; k < HDIM / 4; ++k) {
    float4 xx = a[k], y = w[k];
    s += xx.x * y.x + xx.y * y.y + xx.z * y.z + xx.w * y.w;
  }
  dst[idx] = s;
}

// ---------------- diagnostic (f32) ----------------
__global__ __launch_bounds__(256) void k_diag(float* out, int n, float val) {
  int i = blockIdx.x * 256 + threadIdx.x;
  if (i < n) out[i] = val;
}

extern "C" void kernel_launch(void* const* d_in, const int* in_sizes, int n_in,
                              void* d_out, int out_size, void* d_ws, size_t ws_size,
                              hipStream_t stream) {
  float* outF = (float*)d_out;
  int diag_blocks = (out_size + 255) / 256;

  static const int exp_sizes[19] = {16777216, 1572864, 3145728, 3072, 3072,
                                    1572864, 3145728, 3072, 3072, 2048, 1,
                                    524288, 1024, 1048576, 1024, 1048576, 1024,
                                    1048576, 1024};
  if (n_in != 19) {
    k_diag<<<diag_blocks, 256, 0, stream>>>(outF, out_size, 3999.0f);
    return;
  }
  for (int i = 0; i < 19; ++i) {
    if (in_sizes[i] != exp_sizes[i]) {
      k_diag<<<diag_blocks, 256, 0, stream>>>(outF, out_size, (float)(4000 + i * 16));
      return;
    }
  }

  const float* x     = (const float*)d_in[0];
  const float* wihf32f = (const float*)d_in[1];
  const float* whhf32f = (const float*)d_in[2];
  const float* bih_f = (const float*)d_in[3];
  const float* bhh_f = (const float*)d_in[4];
  const float* wihf32b = (const float*)d_in[5];
  const float* whhf32b = (const float*)d_in[6];
  const float* bih_b = (const float*)d_in[7];
  const float* bhh_b = (const float*)d_in[8];
  const float* fc_w  = (const float*)d_in[9];
  const float* fc_b  = (const float*)d_in[10];
  const float* i2h_w = (const float*)d_in[11];
  const float* i2h_b = (const float*)d_in[12];
  const float* h2h_w = (const float*)d_in[13];
  const float* h2h_b = (const float*)d_in[14];
  const float* fc0_w = (const float*)d_in[15];
  const float* fc0_b = (const float*)d_in[16];
  const float* fc1_w = (const float*)d_in[17];
  const float* fc1_b = (const float*)d_in[18];

  const size_t OFF_XBF   = 0;          // 33,554,432
  const size_t OFF_WIHF  = 33554432;   //  3,145,728
  const size_t OFF_WIHB  = 36700160;   //  3,145,728
  const size_t OFF_WHHF  = 39845888;   //  6,291,456
  const size_t OFF_WHHB  = 46137344;   //  6,291,456
  const size_t OFF_H2H   = 52428800;   //  2,097,152
  const size_t OFF_I2H   = 54525952;   //  1,048,576
  const size_t OFF_ATTP  = 55574528;   // 16,777,216
  const size_t OFF_ATT   = 72351744;   //    131,072
  const size_t OFF_HBUF  = 72482816;   //    524,288
  const size_t OFF_H3BUF = 73007104;   //    262,144
  const size_t OFF_HLAST = 73269248;   //    262,144
  const size_t OFF_OUT1  = 73531392;   //    262,144
  const size_t OFF_FLAGS = 73793536;   //      1,024
  const size_t TOTAL     = 73794560;

  if (ws_size < TOTAL) {
    k_diag<<<diag_blocks, 256, 0, stream>>>(outF, out_size, (float)(ws_size >> 20));
    return;
  }

  char* ws = (char*)d_ws;
  unsigned short* xbf   = (unsigned short*)(ws + OFF_XBF);
  unsigned short* wihf  = (unsigned short*)(ws + OFF_WIHF);
  unsigned short* wihb  = (unsigned short*)(ws + OFF_WIHB);
  unsigned short* whhf  = (unsigned short*)(ws + OFF_WHHF);
  unsigned short* whhb  = (unsigned short*)(ws + OFF_WHHB);
  unsigned short* h2h16 = (unsigned short*)(ws + OFF_H2H);
  unsigned short* i2h16 = (unsigned short*)(ws + OFF_I2H);
  float* attp           = (float*)(ws + OFF_ATTP);
  float* att            = (float*)(ws + OFF_ATT);
  unsigned short* hbuf  = (unsigned short*)(ws + OFF_HBUF);
  unsigned short* h3buf = (unsigned short*)(ws + OFF_H3BUF);
  float* hlast          = (float*)(ws + OFF_HLAST);
  float* out1           = (float*)(ws + OFF_OUT1);
  unsigned int* flags   = (unsigned int*)(ws + OFF_FLAGS);

  hipMemsetAsync(flags, 0, 1024, stream);
  hipMemsetAsync(hbuf, 0, 524288, stream);
  hipMemsetAsync(h3buf, 0, 262144, stream);

  k_xcvt<<<8192, 256, 0, stream>>>(x, xbf);
  k_cvt<<<768, 256, 0, stream>>>(wihf32f, wihf);
  k_cvt<<<768, 256, 0, stream>>>(wihf32b, wihb);
  k_cvt<<<1536, 256, 0, stream>>>(whhf32f, whhf);
  k_cvt<<<1536, 256, 0, stream>>>(whhf32b, whhb);
  k_cvt<<<512, 256, 0, stream>>>(h2h_w, h2h16);
  k_cvt<<<256, 256, 0, stream>>>(i2h_w, i2h16);

  k_gru_fused<<<128, 256, 0, stream>>>(xbf, wihf, wihb, whhf, whhb,
                                       bih_f, bhh_f, bih_b, bhh_b, fc_w,
                                       hbuf, attp, flags);

  k_attf<<<128, 256, 0, stream>>>(attp, fc_b, att, outF + 65536);

  k_scan3<<<64, 256, 0, stream>>>(xbf, i2h16, h2h16, i2h_b, h2h_b, att,
                                  h3buf, hlast, flags + 128);

  k_fc<<<256, 256, 0, stream>>>(hlast, fc0_w, fc0_b, out1);
  k_fc<<<256, 256, 0, stream>>>(out1, fc1_w, fc1_b, outF);
}

// Round 11
// 12836.276 us; speedup vs baseline: 8.4589x; 2.3382x over previous
//
#include <hip/hip_runtime.h>
#include <cstdint>
#include <cstddef>

#define TDIM 512
#define BDIM 64
#define IDIM 512
#define HDIM 1024
#define SPIN_CAP 20000u  // watchdog: converts any deadlock into a wrong answer

typedef __attribute__((ext_vector_type(8))) short s16x8;
typedef __attribute__((ext_vector_type(4))) float f32x4;

__device__ __forceinline__ unsigned short f2bf(float f) {
  unsigned u = __builtin_bit_cast(unsigned, f);
  u += 0x7FFFu + ((u >> 16) & 1u);
  return (unsigned short)(u >> 16);
}
__device__ __forceinline__ float bf2f(unsigned short s) {
  unsigned u = ((unsigned)s) << 16;
  return __builtin_bit_cast(float, u);
}
__device__ __forceinline__ float sigmf(float x) { return 1.0f / (1.0f + __expf(-x)); }
__device__ __forceinline__ unsigned pk2(float a, float b) {
  return (unsigned)f2bf(a) | ((unsigned)f2bf(b) << 16);
}
#define MFMA16(a, b, c) __builtin_amdgcn_mfma_f32_16x16x32_bf16((a), (b), (c), 0, 0, 0)

// LLC-coherent (relaxed system-scope) exchange: plain coalesced loads/stores with
// sc bits, NO cache-maintenance ops (the round-9 killer).
__device__ __forceinline__ s16x8 ld_frag(const unsigned long long* p) {
  union { unsigned long long u[2]; s16x8 s; } c;
  c.u[0] = __hip_atomic_load(p,     __ATOMIC_RELAXED, __HIP_MEMORY_SCOPE_SYSTEM);
  c.u[1] = __hip_atomic_load(p + 1, __ATOMIC_RELAXED, __HIP_MEMORY_SCOPE_SYSTEM);
  return c.s;
}

// ---------------- converts ----------------
__global__ __launch_bounds__(256) void k_xcvt(const float* __restrict__ x,
                                              unsigned short* __restrict__ xbf) {
  int idx = blockIdx.x * 256 + threadIdx.x;  // T*B*I/8 threads
  int i8 = idx * 8;
  int i = i8 & (IDIM - 1);
  int tb = i8 >> 9;
  int t = tb >> 6, b = tb & 63;
  const float* src = x + ((size_t)(b * TDIM + t)) * IDIM + i;
  float4 a = *(const float4*)src;
  float4 c = *(const float4*)(src + 4);
  uint4 v;
  v.x = pk2(a.x, a.y); v.y = pk2(a.z, a.w);
  v.z = pk2(c.x, c.y); v.w = pk2(c.z, c.w);
  *(uint4*)(xbf + i8) = v;
}

__global__ __launch_bounds__(256) void k_cvt(const float* __restrict__ src,
                                             unsigned short* __restrict__ dst) {
  size_t i8 = ((size_t)blockIdx.x * 256 + threadIdx.x) * 8;
  float4 a = *(const float4*)(src + i8);
  float4 c = *(const float4*)(src + i8 + 4);
  uint4 v;
  v.x = pk2(a.x, a.y); v.y = pk2(a.z, a.w);
  v.z = pk2(c.x, c.y); v.w = pk2(c.z, c.w);
  *(uint4*)(dst + i8) = v;
}

// ---------------- fused persistent bidirectional GRU ----------------
// grid = 128 WGs x 256 thr (4 waves). dir = wg>>6, cg = wg&63 owns 16 h-cols.
// Wave wv owns batch m-tile [wv*16, wv*16+16). Weights (whh 96KB + wih 48KB) in LDS.
// h exchanged via relaxed system-scope u64 atomics (row stride = 256 u64 = 1024 bf16);
// one epoch counter per direction.
__global__ __launch_bounds__(256, 1) void k_gru_fused(
    const unsigned short* __restrict__ xbf,
    const unsigned short* __restrict__ wih_f, const unsigned short* __restrict__ wih_b,
    const unsigned short* __restrict__ whh_f, const unsigned short* __restrict__ whh_b,
    const float* __restrict__ bih_f, const float* __restrict__ bhh_f,
    const float* __restrict__ bih_b, const float* __restrict__ bhh_b,
    const float* __restrict__ attw,
    unsigned long long* __restrict__ hbufu, float* __restrict__ attp,
    unsigned int* __restrict__ ep) {
  __shared__ uint4 lds4[147456 / 16];  // 96KB whh + 48KB wih
  char* lds = (char*)lds4;
  const int wg = blockIdx.x, dir = wg >> 6, cg = wg & 63;
  const int tid = threadIdx.x, wv = tid >> 6, l = tid & 63;
  const int r = l & 15, q = l >> 4;
  const int col = cg * 16 + r;
  const unsigned short* wih = dir ? wih_b : wih_f;
  const unsigned short* whh = dir ? whh_b : whh_f;
  const float* bih = dir ? bih_b : bih_f;
  const float* bhh = dir ? bhh_b : bhh_f;
  unsigned int* myep = ep + dir * 32;             // 128B apart
  unsigned long long* hb0 = hbufu + (size_t)dir * 2 * 16384;  // 2 bufs x 16384 u64

  // stage whh: 48 rows (3 gates x 16 cols) x 1024, XOR-swizzled
  for (int it = tid; it < 48 * 128; it += 256) {
    int row = it >> 7, ch = it & 127;
    int g = row >> 4, rr = row & 15;
    uint4 v = *(const uint4*)(whh + ((size_t)(g * HDIM + cg * 16 + rr)) * HDIM + ch * 8);
    *(uint4*)(lds + row * 2048 + ((ch * 16) ^ ((row & 7) << 4))) = v;
  }
  // stage wih: 48 rows x 512
  for (int it = tid; it < 48 * 64; it += 256) {
    int row = it >> 6, ch = it & 63;
    int g = row >> 4, rr = row & 15;
    uint4 v = *(const uint4*)(wih + ((size_t)(g * HDIM + cg * 16 + rr)) * IDIM + ch * 8);
    *(uint4*)(lds + 98304 + row * 1024 + ((ch * 16) ^ ((row & 7) << 4))) = v;
  }
  __syncthreads();

  const float br = bih[col] + bhh[col];
  const float bz = bih[col + HDIM] + bhh[col + HDIM];
  const float bnx = bih[col + 2 * HDIM];
  const float bnh = bhh[col + 2 * HDIM];
  const float wfc = attw[dir * HDIM + col];
  const int swz = (r & 7) << 4;
  float h[4] = {0.f, 0.f, 0.f, 0.f};

  for (int t = 0; t < TDIM; ++t) {
    const int tt = dir ? (TDIM - 1 - t) : t;
    f32x4 aR = {}, aZ = {}, aNx = {}, aNh = {};
    // x-projection: no h dependency -> compute BEFORE the wait (hides spin)
    {
      const unsigned short* px = xbf + ((size_t)(tt * BDIM + wv * 16 + r)) * IDIM + q * 8;
#pragma unroll 4
      for (int kt = 0; kt < 16; ++kt) {
        s16x8 a = *(const s16x8*)(px + kt * 32);
        int kb = q * 16 + kt * 64;
        s16x8 b0 = *(const s16x8*)(lds + 98304 + r * 1024 + (kb ^ swz));
        s16x8 b1 = *(const s16x8*)(lds + 98304 + (16 + r) * 1024 + (kb ^ swz));
        s16x8 b2 = *(const s16x8*)(lds + 98304 + (32 + r) * 1024 + (kb ^ swz));
        aR = MFMA16(a, b0, aR);
        aZ = MFMA16(a, b1, aZ);
        aNx = MFMA16(a, b2, aNx);
      }
    }
    if (t > 0) {
      const unsigned tgt = 64u * (unsigned)t;
      for (unsigned spin = 0;; ++spin) {
        unsigned v = __hip_atomic_load(myep, __ATOMIC_RELAXED, __HIP_MEMORY_SCOPE_SYSTEM);
        if (v >= tgt) break;
        if (spin > SPIN_CAP) break;  // watchdog
        __builtin_amdgcn_s_sleep(2);
      }
      __builtin_amdgcn_sched_barrier(0);
    }
    // h-projection: u64 LLC loads (row stride 256 u64)
    {
      const unsigned long long* ph = hb0 + (size_t)(t & 1) * 16384 + (wv * 16 + r) * 256 + q * 2;
#pragma unroll 8
      for (int kt = 0; kt < 32; ++kt) {
        s16x8 a = ld_frag(ph + kt * 8);
        int kb = q * 16 + kt * 64;
        s16x8 b0 = *(const s16x8*)(lds + r * 2048 + (kb ^ swz));
        s16x8 b1 = *(const s16x8*)(lds + (16 + r) * 2048 + (kb ^ swz));
        s16x8 b2 = *(const s16x8*)(lds + (32 + r) * 2048 + (kb ^ swz));
        aR = MFMA16(a, b0, aR);
        aZ = MFMA16(a, b1, aZ);
        aNh = MFMA16(a, b2, aNh);
      }
    }
    unsigned long long* hn = hb0 + (size_t)((t + 1) & 1) * 16384;
    float* ap = attp + (size_t)wg * (TDIM * BDIM) + tt * BDIM;
#pragma unroll
    for (int j = 0; j < 4; ++j) {
      const int b = wv * 16 + q * 4 + j;
      float rg = sigmf(aR[j] + br);
      float zg = sigmf(aZ[j] + bz);
      float ng = tanhf(aNx[j] + bnx + rg * (aNh[j] + bnh));
      float hv = (1.0f - zg) * ng + zg * h[j];
      h[j] = hv;
      // pack 4 cols (r..r+3) into one u64, store from lanes with r%4==0
      unsigned p2 = pk2(hv, __shfl_xor(hv, 1, 64));
      unsigned p2o = __shfl_xor(p2, 2, 64);
      if ((r & 3) == 0) {
        unsigned long long v64 = (unsigned long long)p2 | ((unsigned long long)p2o << 32);
        __hip_atomic_store(&hn[(size_t)b * 256 + cg * 4 + (r >> 2)], v64,
                           __ATOMIC_RELAXED, __HIP_MEMORY_SCOPE_SYSTEM);
      }
      float s = hv * wfc;
      s += __shfl_xor(s, 1, 64);
      s += __shfl_xor(s, 2, 64);
      s += __shfl_xor(s, 4, 64);
      s += __shfl_xor(s, 8, 64);
      if (r == 0) ap[b] = s;
    }
    // all stores complete (LLC-acked) before the epoch bump; no cache maintenance
    asm volatile("s_waitcnt vmcnt(0)" ::: "memory");
    __syncthreads();
    if (tid == 0)
      __hip_atomic_fetch_add(myep, 1u, __ATOMIC_RELAXED, __HIP_MEMORY_SCOPE_SYSTEM);
  }
}

// ---------------- attention finalize (f32 outputs) ----------------
__global__ __launch_bounds__(256) void k_attf(const float* __restrict__ attp,
                                              const float* __restrict__ fcb,
                                              float* __restrict__ att,
                                              float* __restrict__ att_out) {
  int idx = blockIdx.x * 256 + threadIdx.x;  // T*B
  float s = fcb[0];
  for (int w = 0; w < 128; ++w) s += attp[(size_t)w * (TDIM * BDIM) + idx];
  float a = sigmf(3.0f * s);
  att[idx] = a;
  int t = idx >> 6, b = idx & 63;
  att_out[(size_t)b * TDIM + t] = a;  // att^T, float32
}

// ---------------- fused persistent attention-gated scan ----------------
__global__ __launch_bounds__(256, 1) void k_scan3(
    const unsigned short* __restrict__ xbf,
    const unsigned short* __restrict__ i2h16, const unsigned short* __restrict__ h2h16,
    const float* __restrict__ i2hb, const float* __restrict__ h2hb,
    const float* __restrict__ att,
    unsigned long long* __restrict__ h3u, float* __restrict__ hlast,
    unsigned int* __restrict__ ep3) {
  __shared__ uint4 lds4[49152 / 16];  // 32KB h2h + 16KB i2h
  char* lds = (char*)lds4;
  const int cg = blockIdx.x;
  const int tid = threadIdx.x, wv = tid >> 6, l = tid & 63;
  const int r = l & 15, q = l >> 4;
  const int col = cg * 16 + r;
  for (int it = tid; it < 16 * 128; it += 256) {
    int row = it >> 7, ch = it & 127;
    uint4 v = *(const uint4*)(h2h16 + ((size_t)(cg * 16 + row)) * HDIM + ch * 8);
    *(uint4*)(lds + row * 2048 + ((ch * 16) ^ ((row & 7) << 4))) = v;
  }
  for (int it = tid; it < 16 * 64; it += 256) {
    int row = it >> 6, ch = it & 63;
    uint4 v = *(const uint4*)(i2h16 + ((size_t)(cg * 16 + row)) * IDIM + ch * 8);
    *(uint4*)(lds + 32768 + row * 1024 + ((ch * 16) ^ ((row & 7) << 4))) = v;
  }
  __syncthreads();
  const float bc = i2hb[col] + h2hb[col];
  const int swz = (r & 7) << 4;
  float h[4] = {0.f, 0.f, 0.f, 0.f};
  for (int t = 0; t < TDIM; ++t) {
    f32x4 ac = {};
    // x-projection before the wait
    {
      const unsigned short* px = xbf + ((size_t)(t * BDIM + wv * 16 + r)) * IDIM + q * 8;
#pragma unroll 4
      for (int kt = 0; kt < 16; ++kt) {
        s16x8 a = *(const s16x8*)(px + kt * 32);
        int kb = q * 16 + kt * 64;
        s16x8 b = *(const s16x8*)(lds + 32768 + r * 1024 + (kb ^ swz));
        ac = MFMA16(a, b, ac);
      }
    }
    if (t > 0) {
      const unsigned tgt = 64u * (unsigned)t;
      for (unsigned spin = 0;; ++spin) {
        unsigned v = __hip_atomic_load(ep3, __ATOMIC_RELAXED, __HIP_MEMORY_SCOPE_SYSTEM);
        if (v >= tgt) break;
        if (spin > SPIN_CAP) break;  // watchdog
        __builtin_amdgcn_s_sleep(2);
      }
      __builtin_amdgcn_sched_barrier(0);
    }
    {
      const unsigned long long* ph = h3u + (size_t)(t & 1) * 16384 + (wv * 16 + r) * 256 + q * 2;
#pragma unroll 8
      for (int kt = 0; kt < 32; ++kt) {
        s16x8 a = ld_frag(ph + kt * 8);
        int kb = q * 16 + kt * 64;
        s16x8 b = *(const s16x8*)(lds + r * 2048 + (kb ^ swz));
        ac = MFMA16(a, b, ac);
      }
    }
    unsigned long long* hn = h3u + (size_t)((t + 1) & 1) * 16384;
    const float* ab = att + (size_t)t * BDIM;
#pragma unroll
    for (int j = 0; j < 4; ++j) {
      const int b = wv * 16 + q * 4 + j;
      float tr = fmaxf(ac[j] + bc, 0.0f);
      float a = ab[b];
      float hv = a * tr + (1.0f - a) * h[j];
      h[j] = hv;
      unsigned p2 = pk2(hv, __shfl_xor(hv, 1, 64));
      unsigned p2o = __shfl_xor(p2, 2, 64);
      if ((r & 3) == 0) {
        unsigned long long v64 = (unsigned long long)p2 | ((unsigned long long)p2o << 32);
        __hip_atomic_store(&hn[(size_t)b * 256 + cg * 4 + (r >> 2)], v64,
                           __ATOMIC_RELAXED, __HIP_MEMORY_SCOPE_SYSTEM);
      }
    }
    asm volatile("s_waitcnt vmcnt(0)" ::: "memory");
    __syncthreads();
    if (tid == 0)
      __hip_atomic_fetch_add(ep3, 1u, __ATOMIC_RELAXED, __HIP_MEMORY_SCOPE_SYSTEM);
  }
#pragma unroll
  for (int j = 0; j < 4; ++j) {
    const int b = wv * 16 + q * 4 + j;
    hlast[b * HDIM + col] = h[j];
  }
}

// ---------------- final FC (fp32 in, fp32 out) ----------------
__global__ __launch_bounds__(256) void k_fc(const float* __restrict__ A,
                                            const float* __restrict__ W,
                                            const float* __restrict__ bias,
                                            float* __restrict__ dst) {
  const int idx = blockIdx.x * 256 + threadIdx.x;
  const int rr = idx >> 10, c = idx & 1023;
  const float4* a = (const float4*)(A + (size_t)rr * HDIM);
  const float4* w = (const float4*)(W + (size_t)c * HDIM);
  float s = bias[c];
  for (int k = 0; k < HDIM / 4; ++k) {
    float4 xx = a[k], y = w[k];
    s += xx.x * y.x + xx.y * y.y + xx.z * y.z + xx.w * y.w;
  }
  dst[idx] = s;
}

// ---------------- diagnostic (f32) ----------------
__global__ __launch_bounds__(256) void k_diag(float* out, int n, float val) {
  int i = blockIdx.x * 256 + threadIdx.x;
  if (i < n) out[i] = val;
}

extern "C" void kernel_launch(void* const* d_in, const int* in_sizes, int n_in,
                              void* d_out, int out_size, void* d_ws, size_t ws_size,
                              hipStream_t stream) {
  float* outF = (float*)d_out;
  int diag_blocks = (out_size + 255) / 256;

  static const int exp_sizes[19] = {16777216, 1572864, 3145728, 3072, 3072,
                                    1572864, 3145728, 3072, 3072, 2048, 1,
                                    524288, 1024, 1048576, 1024, 1048576, 1024,
                                    1048576, 1024};
  if (n_in != 19) {
    k_diag<<<diag_blocks, 256, 0, stream>>>(outF, out_size, 3999.0f);
    return;
  }
  for (int i = 0; i < 19; ++i) {
    if (in_sizes[i] != exp_sizes[i]) {
      k_diag<<<diag_blocks, 256, 0, stream>>>(outF, out_size, (float)(4000 + i * 16));
      return;
    }
  }

  const float* x     = (const float*)d_in[0];
  const float* wihf32f = (const float*)d_in[1];
  const float* whhf32f = (const float*)d_in[2];
  const float* bih_f = (const float*)d_in[3];
  const float* bhh_f = (const float*)d_in[4];
  const float* wihf32b = (const float*)d_in[5];
  const float* whhf32b = (const float*)d_in[6];
  const float* bih_b = (const float*)d_in[7];
  const float* bhh_b = (const float*)d_in[8];
  const float* fc_w  = (const float*)d_in[9];
  const float* fc_b  = (const float*)d_in[10];
  const float* i2h_w = (const float*)d_in[11];
  const float* i2h_b = (const float*)d_in[12];
  const float* h2h_w = (const float*)d_in[13];
  const float* h2h_b = (const float*)d_in[14];
  const float* fc0_w = (const float*)d_in[15];
  const float* fc0_b = (const float*)d_in[16];
  const float* fc1_w = (const float*)d_in[17];
  const float* fc1_b = (const float*)d_in[18];

  const size_t OFF_XBF   = 0;          // 33,554,432
  const size_t OFF_WIHF  = 33554432;   //  3,145,728
  const size_t OFF_WIHB  = 36700160;   //  3,145,728
  const size_t OFF_WHHF  = 39845888;   //  6,291,456
  const size_t OFF_WHHB  = 46137344;   //  6,291,456
  const size_t OFF_H2H   = 52428800;   //  2,097,152
  const size_t OFF_I2H   = 54525952;   //  1,048,576
  const size_t OFF_ATTP  = 55574528;   // 16,777,216
  const size_t OFF_ATT   = 72351744;   //    131,072
  const size_t OFF_HBUF  = 72482816;   //    524,288
  const size_t OFF_H3BUF = 73007104;   //    262,144
  const size_t OFF_HLAST = 73269248;   //    262,144
  const size_t OFF_OUT1  = 73531392;   //    262,144
  const size_t OFF_FLAGS = 73793536;   //      1,024
  const size_t TOTAL     = 73794560;

  if (ws_size < TOTAL) {
    k_diag<<<diag_blocks, 256, 0, stream>>>(outF, out_size, (float)(ws_size >> 20));
    return;
  }

  char* ws = (char*)d_ws;
  unsigned short* xbf   = (unsigned short*)(ws + OFF_XBF);
  unsigned short* wihf  = (unsigned short*)(ws + OFF_WIHF);
  unsigned short* wihb  = (unsigned short*)(ws + OFF_WIHB);
  unsigned short* whhf  = (unsigned short*)(ws + OFF_WHHF);
  unsigned short* whhb  = (unsigned short*)(ws + OFF_WHHB);
  unsigned short* h2h16 = (unsigned short*)(ws + OFF_H2H);
  unsigned short* i2h16 = (unsigned short*)(ws + OFF_I2H);
  float* attp           = (float*)(ws + OFF_ATTP);
  float* att            = (float*)(ws + OFF_ATT);
  unsigned long long* hbufu = (unsigned long long*)(ws + OFF_HBUF);
  unsigned long long* h3u   = (unsigned long long*)(ws + OFF_H3BUF);
  float* hlast          = (float*)(ws + OFF_HLAST);
  float* out1           = (float*)(ws + OFF_OUT1);
  unsigned int* flags   = (unsigned int*)(ws + OFF_FLAGS);

  hipMemsetAsync(flags, 0, 1024, stream);
  hipMemsetAsync(hbufu, 0, 524288, stream);
  hipMemsetAsync(h3u, 0, 262144, stream);

  k_xcvt<<<8192, 256, 0, stream>>>(x, xbf);
  k_cvt<<<768, 256, 0, stream>>>(wihf32f, wihf);
  k_cvt<<<768, 256, 0, stream>>>(wihf32b, wihb);
  k_cvt<<<1536, 256, 0, stream>>>(whhf32f, whhf);
  k_cvt<<<1536, 256, 0, stream>>>(whhf32b, whhb);
  k_cvt<<<512, 256, 0, stream>>>(h2h_w, h2h16);
  k_cvt<<<256, 256, 0, stream>>>(i2h_w, i2h16);

  // epochs: dir0 at flags[0], dir1 at flags[32], scan3 at flags[64] (128B apart)
  k_gru_fused<<<128, 256, 0, stream>>>(xbf, wihf, wihb, whhf, whhb,
                                       bih_f, bhh_f, bih_b, bhh_b, fc_w,
                                       hbufu, attp, flags);

  k_attf<<<128, 256, 0, stream>>>(attp, fc_b, att, outF + 65536);

  k_scan3<<<64, 256, 0, stream>>>(xbf, i2h16, h2h16, i2h_b, h2h_b, att,
                                  h3u, hlast, flags + 64);

  k_fc<<<256, 256, 0, stream>>>(hlast, fc0_w, fc0_b, out1);
  k_fc<<<256, 256, 0, stream>>>(out1, fc1_w, fc1_b, outF);
}